// Round 9
// baseline (516.743 us; speedup 1.0000x reference)
//
#include <hip/hip_runtime.h>
#include <hip/hip_fp16.h>

// Problem constants
#define BS    8192
#define DIM   256
#define KTOT  16384      // 128x128 codebook
#define TASK_CAP 131072

typedef __attribute__((ext_vector_type(8))) _Float16 half8;
typedef __attribute__((ext_vector_type(4))) float f32x4;
typedef unsigned long long u64;

__device__ inline ushort f2h(float f) { return __half_as_ushort(__float2half(f)); }

// async global->LDS, 16B per lane; lds dest = wave-uniform base + lane*16
__device__ inline void gload_lds16(const void* g, void* l) {
    __builtin_amdgcn_global_load_lds(
        (const __attribute__((address_space(1))) unsigned int*)g,
        (__attribute__((address_space(3))) unsigned int*)l, 16, 0, 0);
}

// order-preserving f32 -> u32 map (ascending)
__device__ inline unsigned int fmap(float f) {
    unsigned int b = __float_as_uint(f);
    return (b & 0x80000000u) ? ~b : (b | 0x80000000u);
}

// ---------------------------------------------------------------------------
// setup: zero S (16 MB), G table, zero cntf, init keys2, zero task cnt.
__global__ void setup_all_kernel(float* __restrict__ S, float* __restrict__ G,
                                 float* __restrict__ cntf, u64* __restrict__ keys2,
                                 unsigned int* __restrict__ cnt, const int* __restrict__ itp) {
    int idx = blockIdx.x * 256 + threadIdx.x;
    *(float4*)&S[(size_t)idx * 4] = make_float4(0.f, 0.f, 0.f, 0.f);
    if (idx < KTOT) {
        float itf = (float)itp[0];
        const float START_SIGMA = 64.0f;
        const float TAU = (float)(20.0 / 4.1588830833596715);  // 20 / ln(64)
        float sigma = START_SIGMA * expf(-itf / TAU);
        float d2 = 2.0f * sigma * sigma;
        int i = idx >> 7, j = idx & 127;
        float diff = (float)(i - j);
        G[idx] = expf(-(diff * diff) / d2);
        cntf[idx] = 0.f;
    }
    if (idx < BS) keys2[idx] = ~0ULL;
    if (idx == 0) cnt[0] = 0u;
}

// ---------------------------------------------------------------------------
// x,w -> fp16 with XOR-swizzled 32-half windows (conflict-free frag reads),
// + wsq for w rows.  One wave per row; rows [0,BS) are x, [BS,BS+KTOT) are w.
__global__ void cvt_all_kernel(const float* __restrict__ x, const float* __restrict__ w,
                               ushort* __restrict__ xf, ushort* __restrict__ wf,
                               float* __restrict__ wsq) {
    int wid = threadIdx.x >> 6, lane = threadIdx.x & 63;
    int row = blockIdx.x * 4 + wid;
    int h = lane * 4;
    int window = h >> 5, c = (h >> 3) & 3, off = h & 7;
    if (row < BS) {
        int swpos = (window << 5) + ((c ^ ((row >> 1) & 3)) << 3) + off;
        float4 v = *(const float4*)&x[(size_t)row * DIM + h];
        ushort4 hv;
        hv.x = f2h(v.x); hv.y = f2h(v.y); hv.z = f2h(v.z); hv.w = f2h(v.w);
        *(ushort4*)&xf[(size_t)row * DIM + swpos] = hv;
    } else {
        int r = row - BS;
        int swpos = (window << 5) + ((c ^ ((r >> 1) & 3)) << 3) + off;
        float4 v = *(const float4*)&w[(size_t)r * DIM + h];
        ushort4 hv;
        hv.x = f2h(v.x); hv.y = f2h(v.y); hv.z = f2h(v.z); hv.w = f2h(v.w);
        *(ushort4*)&wf[(size_t)r * DIM + swpos] = hv;
        float s = v.x * v.x + v.y * v.y + v.z * v.z + v.w * v.w;
        #pragma unroll
        for (int o = 32; o; o >>= 1) s += __shfl_down(s, o, 64);
        if (lane == 0) wsq[r] = s;
    }
}

// ---------------------------------------------------------------------------
// BMU scan (single pass): fp16 GEMM over all k; per (sample, ktile, wn, lm)
// store quantized min score over that lane's 4 k's (u8, q=(sc+300)/3).
// No cross-lane work in the hot loop; no second GEMM pass needed.
// Grid (64 m-tiles, 12 splits); tile t handled by split t%12 (round-robin).
__global__ __launch_bounds__(256, 3) void bmu_scan_kernel(
    const ushort* __restrict__ xf, const ushort* __restrict__ wf,
    const float* __restrict__ wsq, unsigned char* __restrict__ laneMin) {
    __shared__ ushort A[128 * 32];   //  8 KB
    __shared__ ushort B[128 * 32];   //  8 KB

    int m0 = blockIdx.x * 128;
    int ksplit = blockIdx.y;
    int tid = threadIdx.x, w = tid >> 6, lane = tid & 63;
    int wm = (w & 1) * 64;
    int wnIdx = w >> 1, wn = wnIdx * 64;
    int lm = lane & 15, quad = lane >> 4;
    int sw = (quad ^ ((lm >> 1) & 3)) * 8;   // swizzled frag col (bank-conflict-free)
    int srow = lane >> 2, scol = (lane & 3) * 8;

    for (int kt = 0; kt < 11; ++kt) {
        int tile = kt * 12 + ksplit;
        if (tile >= 128) break;
        int k0 = tile * 128;
        f32x4 acc[4][4];
        #pragma unroll
        for (int mi = 0; mi < 4; ++mi)
            #pragma unroll
            for (int ni = 0; ni < 4; ++ni)
                acc[mi][ni] = (f32x4){0.f, 0.f, 0.f, 0.f};

        for (int kb = 0; kb < DIM; kb += 32) {
            size_t axoff = (size_t)(m0 + w * 32 + srow) * DIM + kb + scol;
            size_t bxoff = (size_t)(k0 + w * 32 + srow) * DIM + kb + scol;
            gload_lds16(xf + axoff,            &A[(w * 32) * 32]);
            gload_lds16(xf + axoff + 16 * DIM, &A[(w * 32 + 16) * 32]);
            gload_lds16(wf + bxoff,            &B[(w * 32) * 32]);
            gload_lds16(wf + bxoff + 16 * DIM, &B[(w * 32 + 16) * 32]);
            __syncthreads();
            half8 av[4], bv[4];
            #pragma unroll
            for (int mi = 0; mi < 4; ++mi)
                av[mi] = *(const half8*)&A[(wm + mi * 16 + lm) * 32 + sw];
            #pragma unroll
            for (int ni = 0; ni < 4; ++ni)
                bv[ni] = *(const half8*)&B[(wn + ni * 16 + lm) * 32 + sw];
            #pragma unroll
            for (int mi = 0; mi < 4; ++mi)
                #pragma unroll
                for (int ni = 0; ni < 4; ++ni)
                    acc[mi][ni] = __builtin_amdgcn_mfma_f32_16x16x32_f16(
                        av[mi], bv[ni], acc[mi][ni], 0, 0, 0);
            __syncthreads();
        }
        // fold: per C-position min over 4 ni scores -> quantize -> u8 store
        float wsqv[4];
        #pragma unroll
        for (int ni = 0; ni < 4; ++ni) wsqv[ni] = wsq[k0 + wn + ni * 16 + lm];
        size_t baseA = ((size_t)(tile * 2 + wnIdx) * 8192 + m0 + wm + quad * 4) * 16 + lm;
        #pragma unroll
        for (int mi = 0; mi < 4; ++mi) {
            #pragma unroll
            for (int r = 0; r < 4; ++r) {
                float s0 = fmaf(-2.0f, acc[mi][0][r], wsqv[0]);
                float s1 = fmaf(-2.0f, acc[mi][1][r], wsqv[1]);
                float s2 = fmaf(-2.0f, acc[mi][2][r], wsqv[2]);
                float s3 = fmaf(-2.0f, acc[mi][3][r], wsqv[3]);
                float m = fminf(fminf(s0, s1), fminf(s2, s3));
                float qf = fminf(fmaxf(rintf(fmaf(m, 0.33333334f, 100.0f)), 0.f), 255.f);
                laneMin[baseA + (size_t)(mi * 16 + r) * 16] = (unsigned char)(int)qf;
            }
        }
    }
}

// ---------------------------------------------------------------------------
// collect: per sample, qmin over its 2048 lane-mins; emit tasks with q<=qmin+2
// (integer threshold provably covers true margin gmin+1.0 incl. quant error).
// Grid 512 blocks (16 samples each); thread=(sl,lm).
__global__ __launch_bounds__(256) void collect_kernel(
    const unsigned char* __restrict__ laneMin, unsigned int* __restrict__ tasks,
    unsigned int* __restrict__ cnt) {
    int tid = threadIdx.x;
    int sl = tid >> 4, lm = tid & 15;
    int s = blockIdx.x * 16 + sl;
    int qmin = 255;
    #pragma unroll 4
    for (int t = 0; t < 256; ++t) {
        int v = laneMin[((size_t)t * 8192 + s) * 16 + lm];
        qmin = v < qmin ? v : qmin;
    }
    #pragma unroll
    for (int mask = 1; mask < 16; mask <<= 1) {
        int o = __shfl_xor(qmin, mask, 64);
        qmin = o < qmin ? o : qmin;
    }
    int thr = qmin + 2;
    #pragma unroll 4
    for (int t = 0; t < 256; ++t) {
        int v = laneMin[((size_t)t * 8192 + s) * 16 + lm];
        if (v <= thr) {
            unsigned int idx = atomicAdd(cnt, 1u);
            if (idx < TASK_CAP)
                tasks[idx] = ((unsigned int)s << 12) | ((unsigned int)t << 4) | (unsigned int)lm;
        }
    }
}

// ---------------------------------------------------------------------------
// rescore: per task, exact f32 dist^2 for the lane's 4 k's; packed atomicMin
// into keys2 (this IS the final exact BMU; replaces refine).
__global__ __launch_bounds__(256) void rescore_kernel(
    const float* __restrict__ x, const float* __restrict__ w,
    const unsigned int* __restrict__ tasks, const unsigned int* __restrict__ cnt,
    u64* __restrict__ keys2) {
    int tid = threadIdx.x;
    int lane = tid & 63;
    int gw = (blockIdx.x * 256 + tid) >> 6;
    unsigned int n = cnt[0];
    if (n > TASK_CAP) n = TASK_CAP;
    int g = lane >> 4, l16 = lane & 15;
    for (unsigned int t = gw; t < n; t += 256 * 4) {
        unsigned int v = tasks[t];
        int lmv = v & 15;
        int tw = (v >> 4) & 255;
        int s = v >> 12;
        int wn = tw & 1, tile = tw >> 1;
        int k = tile * 128 + wn * 64 + g * 16 + lmv;
        float dist = 0.f;
        #pragma unroll
        for (int j = 0; j < 4; ++j) {
            int d = j * 64 + l16 * 4;
            float4 xv = *(const float4*)&x[(size_t)s * DIM + d];
            float4 wv = *(const float4*)&w[(size_t)k * DIM + d];
            float dx = xv.x - wv.x, dy = xv.y - wv.y;
            float dz = xv.z - wv.z, dw = xv.w - wv.w;
            dist += dx * dx + dy * dy + dz * dz + dw * dw;
        }
        #pragma unroll
        for (int mask = 1; mask < 16; mask <<= 1)
            dist += __shfl_xor(dist, mask, 64);
        u64 p = ((u64)fmap(dist) << 32) | (unsigned int)k;
        u64 o = __shfl_xor(p, 16, 64); p = o < p ? o : p;
        o = __shfl_xor(p, 32, 64);     p = o < p ? o : p;
        if (lane == 0) atomicMin(&keys2[s], p);
    }
}

// ---------------------------------------------------------------------------
// scatter: S[bmu(s)][:] += x[s][:], cntf[bmu(s)] += 1.  One wave per sample.
__global__ __launch_bounds__(256) void scatter_kernel(
    const float* __restrict__ x, const u64* __restrict__ keys2,
    float* __restrict__ S, float* __restrict__ cntf) {
    int lane = threadIdx.x & 63;
    int s = blockIdx.x * 4 + (threadIdx.x >> 6);
    unsigned int k = (unsigned int)keys2[s];
    float4 xv = *(const float4*)&x[(size_t)s * DIM + lane * 4];
    float* Sp = &S[(size_t)k * DIM + lane * 4];
    atomicAdd(Sp + 0, xv.x);
    atomicAdd(Sp + 1, xv.y);
    atomicAdd(Sp + 2, xv.z);
    atomicAdd(Sp + 3, xv.w);
    if (lane == 0) atomicAdd(&cntf[k], 1.0f);
}

// ---------------------------------------------------------------------------
// gemm1: T[i][m] = sum_a G[i][a] * S[a][m], m in [0,32768), f32.
__global__ __launch_bounds__(256) void gemm1_kernel(
    const float* __restrict__ G, const float* __restrict__ S, float* __restrict__ T) {
    __shared__ float Sl[128 * 68];
    int n0 = blockIdx.x * 64;
    int tid = threadIdx.x;
    #pragma unroll
    for (int q = 0; q < 8; ++q) {
        int idx = q * 256 + tid;
        int row = idx >> 4, c4 = (idx & 15) * 4;
        *(float4*)&Sl[row * 68 + c4] = *(const float4*)&S[(size_t)row * 32768 + n0 + c4];
    }
    __syncthreads();
    int ng = tid & 15, ig = tid >> 4;
    for (int pass = 0; pass < 2; ++pass) {
        int ibase = pass * 64 + ig * 4;
        float acc[4][4] = {};
        for (int a = 0; a < 128; ++a) {
            float4 sv = *(const float4*)&Sl[a * 68 + ng * 4];
            #pragma unroll
            for (int ii = 0; ii < 4; ++ii) {
                float g = G[(ibase + ii) * 128 + a];
                acc[ii][0] = fmaf(g, sv.x, acc[ii][0]);
                acc[ii][1] = fmaf(g, sv.y, acc[ii][1]);
                acc[ii][2] = fmaf(g, sv.z, acc[ii][2]);
                acc[ii][3] = fmaf(g, sv.w, acc[ii][3]);
            }
        }
        #pragma unroll
        for (int ii = 0; ii < 4; ++ii)
            *(float4*)&T[(size_t)(ibase + ii) * 32768 + n0 + ng * 4] =
                *(float4*)&acc[ii][0];
    }
}

// ---------------------------------------------------------------------------
// denom stage 1: M1[a][j] = sum_b2 cntf[a][b2] * G[b2][j]
__global__ void denom_s1_kernel(const float* __restrict__ cntf, const float* __restrict__ G,
                                float* __restrict__ M1) {
    int a = blockIdx.x, j = threadIdx.x;
    float acc = 0.f;
    for (int b2 = 0; b2 < 128; ++b2)
        acc = fmaf(cntf[a * 128 + b2], G[b2 * 128 + j], acc);
    M1[a * 128 + j] = acc;
}

// denom stage 2: denom[i][j] = sum_a G[i][a] * M1[a][j]
__global__ void denom_s2_kernel(const float* __restrict__ G, const float* __restrict__ M1,
                                float* __restrict__ denom) {
    int i = blockIdx.x, j = threadIdx.x;
    float acc = 0.f;
    for (int a = 0; a < 128; ++a)
        acc = fmaf(G[i * 128 + a], M1[a * 128 + j], acc);
    denom[i * 128 + j] = acc;
}

// ---------------------------------------------------------------------------
// gemm2 + finalize: out[i][j][d] = (sum_b2 G[j][b2] T[i][b2*256+d]) / denom[i][j]
__global__ __launch_bounds__(256) void gemm2_fin_kernel(
    const float* __restrict__ G, const float* __restrict__ T,
    const float* __restrict__ denom, const float* __restrict__ w,
    float* __restrict__ out) {
    __shared__ float Tl[128 * 68];
    int i = blockIdx.x, dq = blockIdx.y;
    int tid = threadIdx.x;
    #pragma unroll
    for (int q = 0; q < 8; ++q) {
        int idx = q * 256 + tid;
        int row = idx >> 4, c4 = (idx & 15) * 4;
        *(float4*)&Tl[row * 68 + c4] =
            *(const float4*)&T[(size_t)i * 32768 + row * 256 + dq * 64 + c4];
    }
    __syncthreads();
    int dg = tid & 15, jg = tid >> 4;
    for (int pass = 0; pass < 2; ++pass) {
        int jbase = pass * 64 + jg * 4;
        float acc[4][4] = {};
        for (int b2 = 0; b2 < 128; ++b2) {
            float4 tv = *(const float4*)&Tl[b2 * 68 + dg * 4];
            #pragma unroll
            for (int jj = 0; jj < 4; ++jj) {
                float g = G[(jbase + jj) * 128 + b2];
                acc[jj][0] = fmaf(g, tv.x, acc[jj][0]);
                acc[jj][1] = fmaf(g, tv.y, acc[jj][1]);
                acc[jj][2] = fmaf(g, tv.z, acc[jj][2]);
                acc[jj][3] = fmaf(g, tv.w, acc[jj][3]);
            }
        }
        #pragma unroll
        for (int jj = 0; jj < 4; ++jj) {
            int j = jbase + jj;
            float dv = denom[i * 128 + j];
            size_t e = (size_t)(i * 128 + j) * DIM + dq * 64 + dg * 4;
            float4 r;
            if (dv != 0.0f) {
                float inv = 1.0f / dv;
                r.x = acc[jj][0] * inv; r.y = acc[jj][1] * inv;
                r.z = acc[jj][2] * inv; r.w = acc[jj][3] * inv;
            } else {
                r = *(const float4*)&w[e];
            }
            *(float4*)&out[e] = r;
        }
    }
}

// ---------------------------------------------------------------------------
extern "C" void kernel_launch(void* const* d_in, const int* in_sizes, int n_in,
                              void* d_out, int out_size, void* d_ws, size_t ws_size,
                              hipStream_t stream) {
    const float* data = (const float*)d_in[0];   // [8192, 256] f32
    const float* w    = (const float*)d_in[1];   // [128,128,256] f32
    const int*   itp  = (const int*)d_in[2];     // scalar
    float* out = (float*)d_out;                  // [128,128,256] f32

    char* ws = (char*)d_ws;
    size_t off = 0;
    float*         wsq     = (float*)(ws + off);         off += 65536;    //  64 KB
    u64*           keys2   = (u64*)(ws + off);           off += 65536;    //  64 KB (exact dist|k)
    unsigned int*  cnt     = (unsigned int*)(ws + off);  off += 65536;    //  64 KB
    float*         G       = (float*)(ws + off);         off += 65536;    //  64 KB
    float*         cntf    = (float*)(ws + off);         off += 65536;    //  64 KB
    float*         M1      = (float*)(ws + off);         off += 65536;    //  64 KB
    float*         denom   = (float*)(ws + off);         off += 65536;    //  64 KB
    ushort*        xf      = (ushort*)(ws + off);        off += 4194304;  //   4 MB fp16 swizzled
    ushort*        wf      = (ushort*)(ws + off);        off += 8388608;  //   8 MB fp16 swizzled
    unsigned int*  tasks   = (unsigned int*)(ws + off);  off += 1048576;  //   1 MB
    float*         S       = (float*)(ws + off);         off += 16777216; //  16 MB [c][d]
    unsigned char* laneMin = (unsigned char*)(ws + off); off += 33554432; //  32 MB [t*2+wn][s][lm]
    float*         T       = (float*)laneMin;            // alias: laneMin dead before gemm1

    setup_all_kernel<<<4096, 256, 0, stream>>>(S, G, cntf, keys2, cnt, itp);
    cvt_all_kernel<<<(BS + KTOT) / 4, 256, 0, stream>>>(data, w, xf, wf, wsq);
    bmu_scan_kernel<<<dim3(64, 12), 256, 0, stream>>>(xf, wf, wsq, laneMin);
    collect_kernel<<<512, 256, 0, stream>>>(laneMin, tasks, cnt);
    rescore_kernel<<<256, 256, 0, stream>>>(data, w, tasks, cnt, keys2);
    scatter_kernel<<<BS / 4, 256, 0, stream>>>(data, keys2, S, cntf);
    gemm1_kernel<<<512, 256, 0, stream>>>(G, S, T);
    denom_s1_kernel<<<128, 128, 0, stream>>>(cntf, G, M1);
    denom_s2_kernel<<<128, 128, 0, stream>>>(G, M1, denom);
    gemm2_fin_kernel<<<dim3(128, 4), 256, 0, stream>>>(G, T, denom, w, out);
}